// Round 8
// baseline (78.327 us; speedup 1.0000x reference)
//
#include <hip/hip_runtime.h>

#define TT 16384      // total tokens
#define DD 2048       // d_model
#define EE 64         // experts
#define KSPLIT 4
#define KSL (DD/KSPLIT)   // 512 k per split
#define TM 64             // tokens per chunk (k1b/k2/k3) and per k1a block
#define NBLK (TT/TM)      // 256
#define CAP 512u          // expert capacity (keep if 1-based position < CAP)

typedef __attribute__((ext_vector_type(8))) short bf16x8;
typedef __attribute__((ext_vector_type(4))) float f32x4;

__device__ __forceinline__ unsigned short f2bf(float x) {   // RNE f32->bf16
    unsigned u = __float_as_uint(x);
    unsigned r = (u + 0x7fffu + ((u >> 16) & 1u)) >> 16;
    return (unsigned short)r;
}
__device__ __forceinline__ float bf2f(unsigned short b) {
    return __uint_as_float(((unsigned)b) << 16);
}

__device__ __forceinline__ bool pair_gt(float va, int ia, float vb, int ib) {
    // jax.lax.top_k ordering: higher value wins; tie -> lower index wins
    return (va > vb) || (va == vb && ia < ib);
}

// k0: W -> frag-ordered bf16 planes (RNE split; tiny kernel, unchanged).
__global__ __launch_bounds__(256) void k0_prep(
    const float* __restrict__ W, unsigned short* __restrict__ Wf)
{
    const int c = blockIdx.x * 256 + threadIdx.x;   // 16384 = 64s*4t*64l
    const int l = c & 63;
    const int t = (c >> 6) & 3;
    const int s = c >> 8;
    const int e = t * 16 + (l & 15);
    const int kk = s * 32 + (l >> 4) * 8;
    const float* wp = W + (size_t)e * DD + kk;
    unsigned short h[8], m[8], lo[8];
    #pragma unroll
    for (int j = 0; j < 8; ++j) {
        const float x = wp[j];
        h[j] = f2bf(x);
        const float r1 = x - bf2f(h[j]);
        m[j] = f2bf(r1);
        lo[j] = f2bf(r1 - bf2f(m[j]));
    }
    const size_t base = ((size_t)(s * 4 + t) * 3) * 64 + l;
    unsigned short* d0 = Wf + (base)      * 8;
    unsigned short* d1 = Wf + (base + 64) * 8;
    unsigned short* d2 = Wf + (base + 128) * 8;
    #pragma unroll
    for (int j = 0; j < 8; ++j) { d0[j] = h[j]; d1[j] = m[j]; d2[j] = lo[j]; }
}

// k1a: partial gate GEMM on matrix cores. grid = NBLK*KSPLIT = 1024, block 256.
// v7: __launch_bounds__(256,4) -> VGPR cap 128 so the 12-frag B preload stays
// in registers (v6's default cap squeezed to 52 VGPR -> serialized
// load->wait->mfma chains, all pipes <16%). Loads issued before the A-split
// VALU; A split by exact truncation (Sterbenz) instead of RNE: ~2x fewer VALU.
__global__ __launch_bounds__(256, 4) void k1a_mfma(
    const float* __restrict__ X, const unsigned short* __restrict__ Wf,
    float* __restrict__ partial)
{
    const int tid = threadIdx.x;
    const int tb = blockIdx.x >> 2;
    const int sp = blockIdx.x & 3;
    const int wv = tid >> 6;
    const int l = tid & 63;
    const int tokb = tb * TM + wv * 16;
    const int row = tokb + (l & 15);

    const float* xp = X + (size_t)row * DD + sp * KSL + (l >> 4) * 8;
    const unsigned short* wbase = Wf + (size_t)l * 8 + (size_t)(sp * 16) * 12 * 512;

    f32x4 acc[4];
    #pragma unroll
    for (int t = 0; t < 4; ++t) acc[t] = (f32x4){0.f, 0.f, 0.f, 0.f};

    float4 xa = *(const float4*)(xp);
    float4 xb = *(const float4*)(xp + 4);

    for (int s = 0; s < 16; ++s) {
        // issue next-step X loads (HBM/L3) as early as possible
        const int sn = (s + 1) & 15;           // s=15: dummy reload of step 0
        const float4 na = *(const float4*)(xp + sn * 32);
        const float4 nb = *(const float4*)(xp + sn * 32 + 4);

        // issue all 12 B loads (L1/L2-hot) before the split VALU
        const unsigned short* ws_ = wbase + (size_t)s * 12 * 512;
        bf16x8 B[4][3];
        #pragma unroll
        for (int t = 0; t < 4; ++t)
            #pragma unroll
            for (int p = 0; p < 3; ++p)
                B[t][p] = *(const bf16x8*)(ws_ + (size_t)(t * 3 + p) * 512);

        // exact truncation 3-plane split (hi=top16 bits; r1=x-hi exact;
        // lo=r1-mid exact & bf16-representable -> bit-truncation packs exact)
        unsigned u[8] = {__float_as_uint(xa.x), __float_as_uint(xa.y),
                         __float_as_uint(xa.z), __float_as_uint(xa.w),
                         __float_as_uint(xb.x), __float_as_uint(xb.y),
                         __float_as_uint(xb.z), __float_as_uint(xb.w)};
        unsigned r1u[8], lfu[8];
        #pragma unroll
        for (int j = 0; j < 8; ++j) {
            const float xf = __uint_as_float(u[j]);
            const float hf = __uint_as_float(u[j] & 0xffff0000u);
            const float r1 = xf - hf;                    // exact
            r1u[j] = __float_as_uint(r1);
            const float mf = __uint_as_float(r1u[j] & 0xffff0000u);
            lfu[j] = __float_as_uint(r1 - mf);           // exact, bf16-exact
        }
        unsigned ah[4], am[4], al[4];
        #pragma unroll
        for (int d = 0; d < 4; ++d) {                    // pack pairs (v_perm)
            ah[d] = (u[2*d]   >> 16) | (u[2*d+1]   & 0xffff0000u);
            am[d] = (r1u[2*d] >> 16) | (r1u[2*d+1] & 0xffff0000u);
            al[d] = (lfu[2*d] >> 16) | (lfu[2*d+1] & 0xffff0000u);
        }
        typedef __attribute__((ext_vector_type(4))) unsigned uint4v;
        const bf16x8 Ah = __builtin_bit_cast(bf16x8, (uint4v){ah[0],ah[1],ah[2],ah[3]});
        const bf16x8 Am = __builtin_bit_cast(bf16x8, (uint4v){am[0],am[1],am[2],am[3]});
        const bf16x8 Al = __builtin_bit_cast(bf16x8, (uint4v){al[0],al[1],al[2],al[3]});

        #pragma unroll
        for (int t = 0; t < 4; ++t) {
            acc[t] = __builtin_amdgcn_mfma_f32_16x16x32_bf16(Ah, B[t][0], acc[t], 0, 0, 0);
            acc[t] = __builtin_amdgcn_mfma_f32_16x16x32_bf16(Ah, B[t][1], acc[t], 0, 0, 0);
            acc[t] = __builtin_amdgcn_mfma_f32_16x16x32_bf16(Am, B[t][0], acc[t], 0, 0, 0);
            acc[t] = __builtin_amdgcn_mfma_f32_16x16x32_bf16(Ah, B[t][2], acc[t], 0, 0, 0);
            acc[t] = __builtin_amdgcn_mfma_f32_16x16x32_bf16(Am, B[t][1], acc[t], 0, 0, 0);
            acc[t] = __builtin_amdgcn_mfma_f32_16x16x32_bf16(Al, B[t][0], acc[t], 0, 0, 0);
        }
        xa = na; xb = nb;
    }

    // writeout: partial[sp][token][expert]
    #pragma unroll
    for (int t = 0; t < 4; ++t) {
        #pragma unroll
        for (int j = 0; j < 4; ++j) {
            const int tok = tokb + (l >> 4) * 4 + j;
            partial[((size_t)sp * TT + tok) * EE + t * 16 + (l & 15)] = acc[t][j];
        }
    }
}

// k1b: combine partials (fixed sp order) + bias + softmax + top2 + stats.
__global__ __launch_bounds__(512) void k1b_epilogue(
    const float* __restrict__ partial, const float* __restrict__ bias,
    uint4* __restrict__ top2, unsigned* __restrict__ counts,
    float* __restrict__ probsum, float* __restrict__ zsum)
{
    __shared__ float Es[TM][EE + 1];
    __shared__ float lseS[TM];
    __shared__ unsigned cnt[EE];

    const int tid = threadIdx.x;
    const int b = blockIdx.x;
    const int tok0 = b * TM;
    const int tok = tid >> 3;
    const int o = tid & 7;
    const int e0 = o * 8;

    if (tid < EE) cnt[tid] = 0;
    __syncthreads();

    float f[8] = {0.f,0.f,0.f,0.f,0.f,0.f,0.f,0.f};
    #pragma unroll
    for (int sp = 0; sp < KSPLIT; ++sp) {
        const float* p = partial + ((size_t)sp * TT + tok0 + tok) * EE + e0;
        const float4 a = *(const float4*)(p);
        const float4 c = *(const float4*)(p + 4);
        f[0]+=a.x; f[1]+=a.y; f[2]+=a.z; f[3]+=a.w;
        f[4]+=c.x; f[5]+=c.y; f[6]+=c.z; f[7]+=c.w;
    }
    #pragma unroll
    for (int j = 0; j < 8; ++j) f[j] += bias[e0 + j];

    float mx = f[0];
    #pragma unroll
    for (int j = 1; j < 8; ++j) mx = fmaxf(mx, f[j]);
    #pragma unroll
    for (int sft = 1; sft < 8; sft <<= 1) mx = fmaxf(mx, __shfl_xor(mx, sft, 64));
    float sum = 0.f;
    #pragma unroll
    for (int j = 0; j < 8; ++j) sum += expf(f[j] - mx);
    #pragma unroll
    for (int sft = 1; sft < 8; sft <<= 1) sum += __shfl_xor(sum, sft, 64);
    const float lse = mx + logf(sum);

    float v1 = f[0]; int i1 = e0;
    float v2 = -3.402823466e38f; int i2 = 0x7fffffff;
    #pragma unroll
    for (int j = 1; j < 8; ++j) {
        const float vv = f[j]; const int e = e0 + j;
        if (pair_gt(vv, e, v1, i1)) { v2 = v1; i2 = i1; v1 = vv; i1 = e; }
        else if (pair_gt(vv, e, v2, i2)) { v2 = vv; i2 = e; }
    }
    #pragma unroll
    for (int sft = 1; sft < 8; sft <<= 1) {
        const float ov1 = __shfl_xor(v1, sft, 64); const int oi1 = __shfl_xor(i1, sft, 64);
        const float ov2 = __shfl_xor(v2, sft, 64); const int oi2 = __shfl_xor(i2, sft, 64);
        if (pair_gt(ov1, oi1, v1, i1)) {
            if (pair_gt(v1, i1, ov2, oi2)) { v2 = v1; i2 = i1; }
            else                            { v2 = ov2; i2 = oi2; }
            v1 = ov1; i1 = oi1;
        } else {
            if (pair_gt(ov1, oi1, v2, i2)) { v2 = ov1; i2 = oi1; }
        }
    }

    #pragma unroll
    for (int j = 0; j < 8; ++j) Es[tok][e0 + j] = expf(f[j] - lse);

    if (o == 0) {
        lseS[tok] = lse;
        top2[tok0 + tok] = make_uint4((unsigned)i1, (unsigned)i2,
                                      __float_as_uint(expf(v1 - lse)),
                                      __float_as_uint(expf(v2 - lse)));
        atomicAdd(&cnt[i1], 1u);
        atomicAdd(&cnt[i2], 1u);
    }
    __syncthreads();

    if (tid < EE) {
        float s = 0.f;
        for (int t = 0; t < TM; ++t) s += Es[t][tid];   // fixed order
        probsum[b * EE + tid] = s;
        counts[b * EE + tid] = cnt[tid];
    }
    if (tid >= 64 && tid < 128) {
        const int t = tid - 64;
        float z = lseS[t]; z = z * z;
        #pragma unroll
        for (int sft = 1; sft < 64; sft <<= 1) z += __shfl_xor(z, sft, 64);
        if (t == 0) zsum[b] = z;
    }
}

// k2: per-expert exclusive prefix over 256 chunks (2-pass) + loss
__global__ __launch_bounds__(256) void k2_scan(
    const unsigned* __restrict__ counts, const float* __restrict__ probsum,
    const float* __restrict__ zsum, unsigned* __restrict__ base,
    float* __restrict__ loss_out)
{
    __shared__ unsigned pc[4][EE];
    __shared__ float pps[4][EE];
    __shared__ float zz[256];
    const int tid = threadIdx.x;
    const int e = tid & 63, q = tid >> 6;
    const int b0 = q * (NBLK / 4), b1 = b0 + (NBLK / 4);

    unsigned csum = 0; float psum_ = 0.f;
    for (int bb = b0; bb < b1; ++bb) {
        csum += counts[bb * EE + e];
        psum_ += probsum[bb * EE + e];
    }
    pc[q][e] = csum; pps[q][e] = psum_;
    zz[tid] = zsum[tid];
    __syncthreads();

    unsigned off = 0;
    for (int qq = 0; qq < q; ++qq) off += pc[qq][e];
    unsigned run = off;
    for (int bb = b0; bb < b1; ++bb) {
        base[bb * EE + e] = run;
        run += counts[bb * EE + e];
    }

    if (q == 0) {
        const unsigned tot = pc[0][e] + pc[1][e] + pc[2][e] + pc[3][e];
        const float pt = pps[0][e] + pps[1][e] + pps[2][e] + pps[3][e];
        float a = (float)tot * pt;
        #pragma unroll
        for (int sft = 1; sft < 64; sft <<= 1) a += __shfl_xor(a, sft, 64);
        float z4 = zz[tid] + zz[tid + 64] + zz[tid + 128] + zz[tid + 192];
        #pragma unroll
        for (int sft = 1; sft < 64; sft <<= 1) z4 += __shfl_xor(z4, sft, 64);
        if (e == 0) {
            const float Tf = (float)TT;
            loss_out[0] = 0.01f * 64.0f * (a / (Tf * Tf)) + z4 / Tf;
        }
    }
}

// k3: capacity ranking within each 64-token chunk + dense mask/weight writes
__global__ __launch_bounds__(256) void k3_write(
    const uint4* __restrict__ top2, const unsigned* __restrict__ base,
    float* __restrict__ mask_out, float* __restrict__ w_out)
{
    __shared__ unsigned ti1[TM], ti2[TM], tk1[TM], tk2[TM];
    __shared__ float tw1[TM], tw2[TM];
    const int b = blockIdx.x, tid = threadIdx.x;
    if (tid < TM) {
        const uint4 v = top2[b * TM + tid];
        ti1[tid] = v.x; ti2[tid] = v.y;
        tw1[tid] = __uint_as_float(v.z); tw2[tid] = __uint_as_float(v.w);
    }
    __syncthreads();
    if (tid < EE) {
        const unsigned e = (unsigned)tid;
        unsigned cc = base[b * EE + tid];
        for (int i = 0; i < TM; ++i) {   // token order = global cumsum order
            if (ti1[i] == e) { cc++; tk1[i] = (cc < CAP); }
            if (ti2[i] == e) { cc++; tk2[i] = (cc < CAP); }
        }
    }
    __syncthreads();
    const int i = tid >> 2, q = tid & 3;
    const unsigned a1 = ti1[i], a2 = ti2[i];
    const unsigned kp1 = tk1[i], kp2 = tk2[i];
    const float w1 = tw1[i], w2 = tw2[i];
    float om[16], ow[16];
    #pragma unroll
    for (int j = 0; j < 16; ++j) {
        const unsigned e = (unsigned)(q * 16 + j);
        float mv = 0.f, wv = 0.f;
        if (e == a1 && kp1) { mv = 1.f; wv = w1; }
        if (e == a2 && kp2) { mv = 1.f; wv = w2; }
        om[j] = mv; ow[j] = wv;
    }
    float* mrow = mask_out + (size_t)(b * TM + i) * EE + q * 16;
    float* wrow = w_out    + (size_t)(b * TM + i) * EE + q * 16;
    #pragma unroll
    for (int j4 = 0; j4 < 4; ++j4) {
        *(float4*)(mrow + j4 * 4) = make_float4(om[j4*4+0], om[j4*4+1], om[j4*4+2], om[j4*4+3]);
        *(float4*)(wrow + j4 * 4) = make_float4(ow[j4*4+0], ow[j4*4+1], ow[j4*4+2], ow[j4*4+3]);
    }
}

extern "C" void kernel_launch(void* const* d_in, const int* in_sizes, int n_in,
                              void* d_out, int out_size, void* d_ws, size_t ws_size,
                              hipStream_t stream)
{
    const float* X    = (const float*)d_in[0];
    const float* W    = (const float*)d_in[1];
    const float* bias = (const float*)d_in[2];
    float* out = (float*)d_out;
    float* mask_out = out;
    float* w_out    = out + (size_t)TT * EE;
    float* loss_out = out + (size_t)2 * TT * EE;

    char* ws = (char*)d_ws;
    unsigned short* Wf = (unsigned short*)ws;                  // 768 KB
    float*    partial = (float*)(ws + 1048576);                // 16 MB
    size_t off = 1048576 + (size_t)KSPLIT * TT * EE * 4;
    uint4*    top2    = (uint4*)(ws + off);      off += (size_t)TT * 16;
    unsigned* counts  = (unsigned*)(ws + off);   off += (size_t)NBLK * EE * 4;
    float*    probsum = (float*)(ws + off);      off += (size_t)NBLK * EE * 4;
    float*    zsum    = (float*)(ws + off);      off += 4096;
    unsigned* base    = (unsigned*)(ws + off);

    k0_prep<<<64, 256, 0, stream>>>(W, Wf);
    k1a_mfma<<<NBLK * KSPLIT, 256, 0, stream>>>(X, Wf, partial);
    k1b_epilogue<<<NBLK, 512, 0, stream>>>(partial, bias, top2, counts, probsum, zsum);
    k2_scan<<<1, 256, 0, stream>>>(counts, probsum, zsum, base, loss_out);
    k3_write<<<NBLK, 256, 0, stream>>>(top2, base, mask_out, w_out);
}

// Round 9
// 62.024 us; speedup vs baseline: 1.2628x; 1.2628x over previous
//
#include <hip/hip_runtime.h>

#define TT 16384      // total tokens
#define DD 2048       // d_model
#define EE 64         // experts
#define KSPLIT 4
#define KSL (DD/KSPLIT)   // 512 k per split
#define TM 64             // tokens per chunk (k1b/k2/k3) and per k1a block
#define NBLK (TT/TM)      // 256
#define CAP 512u          // expert capacity (keep if 1-based position < CAP)

typedef __attribute__((ext_vector_type(8))) short bf16x8;
typedef __attribute__((ext_vector_type(4))) float f32x4;

__device__ __forceinline__ unsigned short f2bf(float x) {   // RNE f32->bf16
    unsigned u = __float_as_uint(x);
    unsigned r = (u + 0x7fffu + ((u >> 16) & 1u)) >> 16;
    return (unsigned short)r;
}
__device__ __forceinline__ float bf2f(unsigned short b) {
    return __uint_as_float(((unsigned)b) << 16);
}

__device__ __forceinline__ bool pair_gt(float va, int ia, float vb, int ib) {
    // jax.lax.top_k ordering: higher value wins; tie -> lower index wins
    return (va > vb) || (va == vb && ia < ib);
}

__device__ __forceinline__ void gload_lds16(const void* g, void* l) {
    // async global->LDS, 16B per lane; LDS dest = uniform base + lane*16
    __builtin_amdgcn_global_load_lds(
        (const __attribute__((address_space(1))) void*)g,
        (__attribute__((address_space(3))) void*)l,
        16, 0, 0);
}

// k0: W -> frag-ordered bf16 planes (RNE split; tiny kernel, unchanged).
// chunk (s_g, t, p) at ushort offset ((s_g*4+t)*3+p)*512; lane frag at +l*8.
__global__ __launch_bounds__(256) void k0_prep(
    const float* __restrict__ W, unsigned short* __restrict__ Wf)
{
    const int c = blockIdx.x * 256 + threadIdx.x;   // 16384 = 64s*4t*64l
    const int l = c & 63;
    const int t = (c >> 6) & 3;
    const int s = c >> 8;
    const int e = t * 16 + (l & 15);
    const int kk = s * 32 + (l >> 4) * 8;
    const float* wp = W + (size_t)e * DD + kk;
    unsigned short h[8], m[8], lo[8];
    #pragma unroll
    for (int j = 0; j < 8; ++j) {
        const float x = wp[j];
        h[j] = f2bf(x);
        const float r1 = x - bf2f(h[j]);
        m[j] = f2bf(r1);
        lo[j] = f2bf(r1 - bf2f(m[j]));
    }
    const size_t base = ((size_t)(s * 4 + t) * 3) * 64 + l;
    unsigned short* d0 = Wf + (base)      * 8;
    unsigned short* d1 = Wf + (base + 64) * 8;
    unsigned short* d2 = Wf + (base + 128) * 8;
    #pragma unroll
    for (int j = 0; j < 8; ++j) { d0[j] = h[j]; d1[j] = m[j]; d2[j] = lo[j]; }
}

// k1a: partial gate GEMM on matrix cores. grid = NBLK*KSPLIT = 1024, block 256.
// v8: B staged once per BLOCK via global_load_lds (12 async DMA/step, 3 per
// wave), double-buffered 2x12KB; each wave ds_read_b128's its frags. Kills
// v7's 4x-redundant per-wave flat loads + serialized vmcnt chains (wall 80us
// vs 9us busy). X stays per-lane VMEM with 1-step prefetch.
__global__ __launch_bounds__(256, 6) void k1a_mfma(
    const float* __restrict__ X, const unsigned short* __restrict__ Wf,
    float* __restrict__ partial)
{
    __shared__ unsigned short Bs[2][12 * 512];   // [buf][chunk*512 + l*8]

    const int tid = threadIdx.x;
    const int tb = blockIdx.x >> 2;
    const int sp = blockIdx.x & 3;
    const int wv = tid >> 6;
    const int l = tid & 63;
    const int tokb = tb * TM + wv * 16;
    const int row = tokb + (l & 15);

    const float* xp = X + (size_t)row * DD + sp * KSL + (l >> 4) * 8;
    const char* wfb = (const char*)Wf;
    const int c0 = wv * 3;                       // this wave stages chunks c0..c0+2
    const int sg0 = sp * 16;                     // global 32k-step base

    f32x4 acc[4];
    #pragma unroll
    for (int t = 0; t < 4; ++t) acc[t] = (f32x4){0.f, 0.f, 0.f, 0.f};

    // prologue: stage step 0 into buf 0
    #pragma unroll
    for (int c = 0; c < 3; ++c)
        gload_lds16(wfb + ((size_t)((sg0 + 0) * 12 + c0 + c) << 10) + (l << 4),
                    (char*)&Bs[0][0] + ((c0 + c) << 10));

    float4 xa = *(const float4*)(xp);
    float4 xb = *(const float4*)(xp + 4);
    __syncthreads();                             // staging 0 complete

    for (int s = 0; s < 16; ++s) {
        // stage next step's B into the other buffer (async DMA)
        if (s + 1 < 16) {
            const int nb = (s + 1) & 1;
            #pragma unroll
            for (int c = 0; c < 3; ++c)
                gload_lds16(wfb + ((size_t)((sg0 + s + 1) * 12 + c0 + c) << 10) + (l << 4),
                            (char*)&Bs[nb][0] + ((c0 + c) << 10));
        }
        // prefetch next X (dummy wrap at s=15)
        const int sn = (s + 1) & 15;
        const float4 na = *(const float4*)(xp + sn * 32);
        const float4 nb_ = *(const float4*)(xp + sn * 32 + 4);

        // exact truncation 3-plane split of current X
        unsigned u[8] = {__float_as_uint(xa.x), __float_as_uint(xa.y),
                         __float_as_uint(xa.z), __float_as_uint(xa.w),
                         __float_as_uint(xb.x), __float_as_uint(xb.y),
                         __float_as_uint(xb.z), __float_as_uint(xb.w)};
        unsigned r1u[8], lfu[8];
        #pragma unroll
        for (int j = 0; j < 8; ++j) {
            const float xf = __uint_as_float(u[j]);
            const float hf = __uint_as_float(u[j] & 0xffff0000u);
            const float r1 = xf - hf;                    // exact (Sterbenz)
            r1u[j] = __float_as_uint(r1);
            const float mf = __uint_as_float(r1u[j] & 0xffff0000u);
            lfu[j] = __float_as_uint(r1 - mf);           // exact, bf16-exact
        }
        unsigned ah[4], am[4], al[4];
        #pragma unroll
        for (int d = 0; d < 4; ++d) {                    // pack pairs (v_perm)
            ah[d] = (u[2*d]   >> 16) | (u[2*d+1]   & 0xffff0000u);
            am[d] = (r1u[2*d] >> 16) | (r1u[2*d+1] & 0xffff0000u);
            al[d] = (lfu[2*d] >> 16) | (lfu[2*d+1] & 0xffff0000u);
        }
        typedef __attribute__((ext_vector_type(4))) unsigned uint4v;
        const bf16x8 Ah = __builtin_bit_cast(bf16x8, (uint4v){ah[0],ah[1],ah[2],ah[3]});
        const bf16x8 Am = __builtin_bit_cast(bf16x8, (uint4v){am[0],am[1],am[2],am[3]});
        const bf16x8 Al = __builtin_bit_cast(bf16x8, (uint4v){al[0],al[1],al[2],al[3]});

        // B frags from LDS (conflict-free b128: lane-linear 16B stride)
        const unsigned short* bb = &Bs[s & 1][l * 8];
        #pragma unroll
        for (int t = 0; t < 4; ++t) {
            bf16x8 B0 = *(const bf16x8*)(bb + (t * 3 + 0) * 512);
            bf16x8 B1 = *(const bf16x8*)(bb + (t * 3 + 1) * 512);
            bf16x8 B2 = *(const bf16x8*)(bb + (t * 3 + 2) * 512);
            acc[t] = __builtin_amdgcn_mfma_f32_16x16x32_bf16(Ah, B0, acc[t], 0, 0, 0);
            acc[t] = __builtin_amdgcn_mfma_f32_16x16x32_bf16(Ah, B1, acc[t], 0, 0, 0);
            acc[t] = __builtin_amdgcn_mfma_f32_16x16x32_bf16(Am, B0, acc[t], 0, 0, 0);
            acc[t] = __builtin_amdgcn_mfma_f32_16x16x32_bf16(Ah, B2, acc[t], 0, 0, 0);
            acc[t] = __builtin_amdgcn_mfma_f32_16x16x32_bf16(Am, B1, acc[t], 0, 0, 0);
            acc[t] = __builtin_amdgcn_mfma_f32_16x16x32_bf16(Al, B0, acc[t], 0, 0, 0);
        }
        __syncthreads();   // drains staging DMA; orders buf reuse
        xa = na; xb = nb_;
    }

    // writeout: partial[sp][token][expert]
    #pragma unroll
    for (int t = 0; t < 4; ++t) {
        #pragma unroll
        for (int j = 0; j < 4; ++j) {
            const int tok = tokb + (l >> 4) * 4 + j;
            partial[((size_t)sp * TT + tok) * EE + t * 16 + (l & 15)] = acc[t][j];
        }
    }
}

// k1b: combine partials (fixed sp order) + bias + softmax + top2 + stats.
__global__ __launch_bounds__(512) void k1b_epilogue(
    const float* __restrict__ partial, const float* __restrict__ bias,
    uint4* __restrict__ top2, unsigned* __restrict__ counts,
    float* __restrict__ probsum, float* __restrict__ zsum)
{
    __shared__ float Es[TM][EE + 1];
    __shared__ float lseS[TM];
    __shared__ unsigned cnt[EE];

    const int tid = threadIdx.x;
    const int b = blockIdx.x;
    const int tok0 = b * TM;
    const int tok = tid >> 3;
    const int o = tid & 7;
    const int e0 = o * 8;

    if (tid < EE) cnt[tid] = 0;
    __syncthreads();

    float f[8] = {0.f,0.f,0.f,0.f,0.f,0.f,0.f,0.f};
    #pragma unroll
    for (int sp = 0; sp < KSPLIT; ++sp) {
        const float* p = partial + ((size_t)sp * TT + tok0 + tok) * EE + e0;
        const float4 a = *(const float4*)(p);
        const float4 c = *(const float4*)(p + 4);
        f[0]+=a.x; f[1]+=a.y; f[2]+=a.z; f[3]+=a.w;
        f[4]+=c.x; f[5]+=c.y; f[6]+=c.z; f[7]+=c.w;
    }
    #pragma unroll
    for (int j = 0; j < 8; ++j) f[j] += bias[e0 + j];

    float mx = f[0];
    #pragma unroll
    for (int j = 1; j < 8; ++j) mx = fmaxf(mx, f[j]);
    #pragma unroll
    for (int sft = 1; sft < 8; sft <<= 1) mx = fmaxf(mx, __shfl_xor(mx, sft, 64));
    float sum = 0.f;
    #pragma unroll
    for (int j = 0; j < 8; ++j) sum += expf(f[j] - mx);
    #pragma unroll
    for (int sft = 1; sft < 8; sft <<= 1) sum += __shfl_xor(sum, sft, 64);
    const float lse = mx + logf(sum);

    float v1 = f[0]; int i1 = e0;
    float v2 = -3.402823466e38f; int i2 = 0x7fffffff;
    #pragma unroll
    for (int j = 1; j < 8; ++j) {
        const float vv = f[j]; const int e = e0 + j;
        if (pair_gt(vv, e, v1, i1)) { v2 = v1; i2 = i1; v1 = vv; i1 = e; }
        else if (pair_gt(vv, e, v2, i2)) { v2 = vv; i2 = e; }
    }
    #pragma unroll
    for (int sft = 1; sft < 8; sft <<= 1) {
        const float ov1 = __shfl_xor(v1, sft, 64); const int oi1 = __shfl_xor(i1, sft, 64);
        const float ov2 = __shfl_xor(v2, sft, 64); const int oi2 = __shfl_xor(i2, sft, 64);
        if (pair_gt(ov1, oi1, v1, i1)) {
            if (pair_gt(v1, i1, ov2, oi2)) { v2 = v1; i2 = i1; }
            else                            { v2 = ov2; i2 = oi2; }
            v1 = ov1; i1 = oi1;
        } else {
            if (pair_gt(ov1, oi1, v2, i2)) { v2 = ov1; i2 = oi1; }
        }
    }

    #pragma unroll
    for (int j = 0; j < 8; ++j) Es[tok][e0 + j] = expf(f[j] - lse);

    if (o == 0) {
        lseS[tok] = lse;
        top2[tok0 + tok] = make_uint4((unsigned)i1, (unsigned)i2,
                                      __float_as_uint(expf(v1 - lse)),
                                      __float_as_uint(expf(v2 - lse)));
        atomicAdd(&cnt[i1], 1u);
        atomicAdd(&cnt[i2], 1u);
    }
    __syncthreads();

    if (tid < EE) {
        float s = 0.f;
        for (int t = 0; t < TM; ++t) s += Es[t][tid];   // fixed order
        probsum[b * EE + tid] = s;
        counts[b * EE + tid] = cnt[tid];
    }
    if (tid >= 64 && tid < 128) {
        const int t = tid - 64;
        float z = lseS[t]; z = z * z;
        #pragma unroll
        for (int sft = 1; sft < 64; sft <<= 1) z += __shfl_xor(z, sft, 64);
        if (t == 0) zsum[b] = z;
    }
}

// k2: per-expert exclusive prefix over 256 chunks (2-pass) + loss
__global__ __launch_bounds__(256) void k2_scan(
    const unsigned* __restrict__ counts, const float* __restrict__ probsum,
    const float* __restrict__ zsum, unsigned* __restrict__ base,
    float* __restrict__ loss_out)
{
    __shared__ unsigned pc[4][EE];
    __shared__ float pps[4][EE];
    __shared__ float zz[256];
    const int tid = threadIdx.x;
    const int e = tid & 63, q = tid >> 6;
    const int b0 = q * (NBLK / 4), b1 = b0 + (NBLK / 4);

    unsigned csum = 0; float psum_ = 0.f;
    for (int bb = b0; bb < b1; ++bb) {
        csum += counts[bb * EE + e];
        psum_ += probsum[bb * EE + e];
    }
    pc[q][e] = csum; pps[q][e] = psum_;
    zz[tid] = zsum[tid];
    __syncthreads();

    unsigned off = 0;
    for (int qq = 0; qq < q; ++qq) off += pc[qq][e];
    unsigned run = off;
    for (int bb = b0; bb < b1; ++bb) {
        base[bb * EE + e] = run;
        run += counts[bb * EE + e];
    }

    if (q == 0) {
        const unsigned tot = pc[0][e] + pc[1][e] + pc[2][e] + pc[3][e];
        const float pt = pps[0][e] + pps[1][e] + pps[2][e] + pps[3][e];
        float a = (float)tot * pt;
        #pragma unroll
        for (int sft = 1; sft < 64; sft <<= 1) a += __shfl_xor(a, sft, 64);
        float z4 = zz[tid] + zz[tid + 64] + zz[tid + 128] + zz[tid + 192];
        #pragma unroll
        for (int sft = 1; sft < 64; sft <<= 1) z4 += __shfl_xor(z4, sft, 64);
        if (e == 0) {
            const float Tf = (float)TT;
            loss_out[0] = 0.01f * 64.0f * (a / (Tf * Tf)) + z4 / Tf;
        }
    }
}

// k3: capacity ranking within each 64-token chunk + dense mask/weight writes
__global__ __launch_bounds__(256) void k3_write(
    const uint4* __restrict__ top2, const unsigned* __restrict__ base,
    float* __restrict__ mask_out, float* __restrict__ w_out)
{
    __shared__ unsigned ti1[TM], ti2[TM], tk1[TM], tk2[TM];
    __shared__ float tw1[TM], tw2[TM];
    const int b = blockIdx.x, tid = threadIdx.x;
    if (tid < TM) {
        const uint4 v = top2[b * TM + tid];
        ti1[tid] = v.x; ti2[tid] = v.y;
        tw1[tid] = __uint_as_float(v.z); tw2[tid] = __uint_as_float(v.w);
    }
    __syncthreads();
    if (tid < EE) {
        const unsigned e = (unsigned)tid;
        unsigned cc = base[b * EE + tid];
        for (int i = 0; i < TM; ++i) {   // token order = global cumsum order
            if (ti1[i] == e) { cc++; tk1[i] = (cc < CAP); }
            if (ti2[i] == e) { cc++; tk2[i] = (cc < CAP); }
        }
    }
    __syncthreads();
    const int i = tid >> 2, q = tid & 3;
    const unsigned a1 = ti1[i], a2 = ti2[i];
    const unsigned kp1 = tk1[i], kp2 = tk2[i];
    const float w1 = tw1[i], w2 = tw2[i];
    float om[16], ow[16];
    #pragma unroll
    for (int j = 0; j < 16; ++j) {
        const unsigned e = (unsigned)(q * 16 + j);
        float mv = 0.f, wv = 0.f;
        if (e == a1 && kp1) { mv = 1.f; wv = w1; }
        if (e == a2 && kp2) { mv = 1.f; wv = w2; }
        om[j] = mv; ow[j] = wv;
    }
    float* mrow = mask_out + (size_t)(b * TM + i) * EE + q * 16;
    float* wrow = w_out    + (size_t)(b * TM + i) * EE + q * 16;
    #pragma unroll
    for (int j4 = 0; j4 < 4; ++j4) {
        *(float4*)(mrow + j4 * 4) = make_float4(om[j4*4+0], om[j4*4+1], om[j4*4+2], om[j4*4+3]);
        *(float4*)(wrow + j4 * 4) = make_float4(ow[j4*4+0], ow[j4*4+1], ow[j4*4+2], ow[j4*4+3]);
    }
}

extern "C" void kernel_launch(void* const* d_in, const int* in_sizes, int n_in,
                              void* d_out, int out_size, void* d_ws, size_t ws_size,
                              hipStream_t stream)
{
    const float* X    = (const float*)d_in[0];
    const float* W    = (const float*)d_in[1];
    const float* bias = (const float*)d_in[2];
    float* out = (float*)d_out;
    float* mask_out = out;
    float* w_out    = out + (size_t)TT * EE;
    float* loss_out = out + (size_t)2 * TT * EE;

    char* ws = (char*)d_ws;
    unsigned short* Wf = (unsigned short*)ws;                  // 768 KB
    float*    partial = (float*)(ws + 1048576);                // 16 MB
    size_t off = 1048576 + (size_t)KSPLIT * TT * EE * 4;
    uint4*    top2    = (uint4*)(ws + off);      off += (size_t)TT * 16;
    unsigned* counts  = (unsigned*)(ws + off);   off += (size_t)NBLK * EE * 4;
    float*    probsum = (float*)(ws + off);      off += (size_t)NBLK * EE * 4;
    float*    zsum    = (float*)(ws + off);      off += 4096;
    unsigned* base    = (unsigned*)(ws + off);

    k0_prep<<<64, 256, 0, stream>>>(W, Wf);
    k1a_mfma<<<NBLK * KSPLIT, 256, 0, stream>>>(X, Wf, partial);
    k1b_epilogue<<<NBLK, 512, 0, stream>>>(partial, bias, top2, counts, probsum, zsum);
    k2_scan<<<1, 256, 0, stream>>>(counts, probsum, zsum, base, loss_out);
    k3_write<<<NBLK, 256, 0, stream>>>(top2, base, mask_out, w_out);
}